// Round 16
// baseline (123.546 us; speedup 1.0000x reference)
//
#include <hip/hip_runtime.h>
#include <hip/hip_bf16.h>
#include <stdint.h>

#define B_N   32
#define T_N   8192
#define D_N   256
#define CTX_N 128
#define TB    32                      /* rows per chunk           */
#define CPB   16                      /* chunks per block         */
#define ROWS_PB (TB*CPB)              /* 512 rows per block       */
#define BLK_PER_B (T_N/ROWS_PB)       /* 16 blocks per batch      */
#define NBLOCKS (B_N*BLK_PER_B)       /* 512                      */
#define XP    264                     /* bf16 pitch (528 B rows)  */
#define SPW   12                      /* s_part row width (floats), 48B */

typedef unsigned short u16;
typedef unsigned int   u32;
typedef __attribute__((ext_vector_type(8))) short bf16x8;
typedef __attribute__((ext_vector_type(8))) unsigned short u16x8;
typedef __attribute__((ext_vector_type(4))) float f32x4;

__device__ __forceinline__ u16 f2bf(float f) {   /* compiler cast (RNE) */
  __hip_bfloat16 h = __float2bfloat16(f);
  return *reinterpret_cast<u16*>(&h);
}
__device__ __forceinline__ float bf2f(u16 h) {
  return __uint_as_float(((u32)h) << 16);
}
__device__ __forceinline__ float fast_tanh(float x) {
  float e = __expf(2.0f * x);
  return (e - 1.0f) * __builtin_amdgcn_rcpf(e + 1.0f);
}
/* 16-lane rotate-reduce on the VALU (DPP row_ror) — off the DS pipe.
   Leaves the full 16-lane sum in EVERY lane of the group. */
__device__ __forceinline__ float rr16_add(float v) {
  int x;
  x = __builtin_amdgcn_update_dpp(0, __float_as_int(v), 0x128, 0xF, 0xF, true); v += __int_as_float(x);
  x = __builtin_amdgcn_update_dpp(0, __float_as_int(v), 0x124, 0xF, 0xF, true); v += __int_as_float(x);
  x = __builtin_amdgcn_update_dpp(0, __float_as_int(v), 0x122, 0xF, 0xF, true); v += __int_as_float(x);
  x = __builtin_amdgcn_update_dpp(0, __float_as_int(v), 0x121, 0xF, 0xF, true); v += __int_as_float(x);
  return v;
}

/* ---------- kernel 1: fused scores+softmax+wsum ----------
   Round-15 structure, ONE change: __launch_bounds__(512,6) -> target
   3 blocks/CU (24 waves). LDS/block = 53.9 KB, 3x = 161.7 KB <= 160 KiB+pad. */
__global__ __launch_bounds__(512, 6)
void attn_main(const float* __restrict__ X, const float* __restrict__ W,
               const float* __restrict__ u,
               float* __restrict__ blk_o, float* __restrict__ blk_l) {
  __shared__ u16   Xl[3][TB][XP];                    /* 50688 B triple-buffer */
  __shared__ __align__(16) float s_part[2][TB][SPW]; /* 3072 B, parity       */
  __shared__ float l_part[16];

  const int tid = threadIdx.x;
  const int w   = tid >> 6;           /* wave 0..7: owns ctx cols w*16..+15 */
  const int l   = tid & 63;
  const int l15 = l & 15;
  const int lg  = l >> 4;

  const int blk  = blockIdx.x;
  const int b    = blk >> 4;                          /* / BLK_PER_B */
  const int rowB = (blk & (BLK_PER_B - 1)) * ROWS_PB;
  const float* Xbase = X + ((size_t)b * T_N + rowB) * D_N;

  /* staging map: thread = (row srow, 16-float segment scol) */
  const int srow = tid >> 4;          /* 0..31 */
  const int scol = (tid & 15) << 4;   /* 0,16,...,240 */
  const float* Xrow = Xbase + (size_t)srow * D_N + scol;

  /* ---- issue chunk-0 HBM prefetch FIRST (long latency) ---- */
  float4 pf0, pf1, pf2, pf3;
  pf0 = ((const float4*)Xrow)[0]; pf1 = ((const float4*)Xrow)[1];
  pf2 = ((const float4*)Xrow)[2]; pf3 = ((const float4*)Xrow)[3];

  /* ---- W^T fragments gathered from fp32 W (hidden under chunk-0 latency) ---- */
  bf16x8 bw[8];
  {
    const float* wcol = W + (w * 16 + l15);
    #pragma unroll
    for (int kk = 0; kk < 8; ++kk) {
      #pragma unroll
      for (int j = 0; j < 8; ++j)
        bw[kk][j] = (short)f2bf(wcol[(size_t)(kk * 32 + lg * 8 + j) * CTX_N]);
    }
  }
  const float uc = u[w * 16 + l15];

  /* wsum map: thread = (t-pair g, d8 slice) */
  const int g     = tid >> 5;         /* 0..15 -> rows 2g,2g+1 */
  const int slice = tid & 31;         /* d = slice*8 .. +8     */
  float o8[8] = {0,0,0,0,0,0,0,0};
  float l_run = 0.f;

  /* deferred weighted-sum for chunk m (reads s_part[m&1], Xl[m%3]) */
  auto wsum = [&](int m) {
    const int pb = m % 3, sp = m & 1;
    float4 sa0 = *(const float4*)&s_part[sp][2 * g][0];
    float4 sa1 = *(const float4*)&s_part[sp][2 * g][4];
    float4 sb0 = *(const float4*)&s_part[sp][2 * g + 1][0];
    float4 sb1 = *(const float4*)&s_part[sp][2 * g + 1][4];
    float st0 = sa0.x; st0 += sa0.y; st0 += sa0.z; st0 += sa0.w;
    st0 += sa1.x; st0 += sa1.y; st0 += sa1.z; st0 += sa1.w;
    float st1 = sb0.x; st1 += sb0.y; st1 += sb0.z; st1 += sb0.w;
    st1 += sb1.x; st1 += sb1.y; st1 += sb1.z; st1 += sb1.w;
    float p0 = __expf(st0), p1 = __expf(st1);
    if (slice == 0) l_run += p0 + p1;
    u16x8 x0 = *(const u16x8*)&Xl[pb][2 * g][slice * 8];
    u16x8 x1 = *(const u16x8*)&Xl[pb][2 * g + 1][slice * 8];
    #pragma unroll
    for (int j = 0; j < 8; ++j) o8[j] += p0 * bf2f(x0[j]) + p1 * bf2f(x1[j]);
  };

  for (int c = 0; c < CPB; ++c) {
    const int cb = c % 3;

    /* ---- stage chunk c (fp32 regs -> bf16 LDS buf[c%3]) ---- */
    u16x8 s0, s1;
    s0[0]=f2bf(pf0.x); s0[1]=f2bf(pf0.y); s0[2]=f2bf(pf0.z); s0[3]=f2bf(pf0.w);
    s0[4]=f2bf(pf1.x); s0[5]=f2bf(pf1.y); s0[6]=f2bf(pf1.z); s0[7]=f2bf(pf1.w);
    s1[0]=f2bf(pf2.x); s1[1]=f2bf(pf2.y); s1[2]=f2bf(pf2.z); s1[3]=f2bf(pf2.w);
    s1[4]=f2bf(pf3.x); s1[5]=f2bf(pf3.y); s1[6]=f2bf(pf3.z); s1[7]=f2bf(pf3.w);
    *(u16x8*)&Xl[cb][srow][scol]     = s0;
    *(u16x8*)&Xl[cb][srow][scol + 8] = s1;

    /* ---- issue next chunk's global loads (fly across the barrier) ---- */
    if (c + 1 < CPB) {
      const float* sp_ = Xrow + (size_t)(c + 1) * TB * D_N;
      pf0 = ((const float4*)sp_)[0]; pf1 = ((const float4*)sp_)[1];
      pf2 = ((const float4*)sp_)[2]; pf3 = ((const float4*)sp_)[3];
    }

    asm volatile("s_waitcnt lgkmcnt(0)" ::: "memory");
    __builtin_amdgcn_s_barrier();     /* buf[c%3] + s_part[(c-1)&1] ready */
    asm volatile("" ::: "memory");

    /* ---- deferred wsum for chunk c-1 (overlaps MFMA region) ---- */
    if (c >= 1) wsum(c - 1);

    /* ---- scores chunk c: 32 rows x (this wave's 16 ctx cols), K=256 ---- */
    const u16* Xc = &Xl[cb][0][0];
    f32x4 acc0 = {0,0,0,0}, acc1 = {0,0,0,0};
    #pragma unroll
    for (int kk = 0; kk < 8; ++kk) {
      bf16x8 a0 = *(const bf16x8*)(Xc + l15 * XP + kk * 32 + lg * 8);
      bf16x8 a1 = *(const bf16x8*)(Xc + (16 + l15) * XP + kk * 32 + lg * 8);
      acc0 = __builtin_amdgcn_mfma_f32_16x16x32_bf16(a0, bw[kk], acc0, 0, 0, 0);
      acc1 = __builtin_amdgcn_mfma_f32_16x16x32_bf16(a1, bw[kk], acc1, 0, 0, 0);
    }
    /* s-partials: DPP reduce leaves sums in ALL lanes; select by l15 and
       write rows lg*4+l15 with lanes l15<4 -> 2 ds_write_b32 (was 8). */
    {
      float sv0 = rr16_add(uc * fast_tanh(acc0[0]));
      float sv1 = rr16_add(uc * fast_tanh(acc0[1]));
      float sv2 = rr16_add(uc * fast_tanh(acc0[2]));
      float sv3 = rr16_add(uc * fast_tanh(acc0[3]));
      float tv0 = rr16_add(uc * fast_tanh(acc1[0]));
      float tv1 = rr16_add(uc * fast_tanh(acc1[1]));
      float tv2 = rr16_add(uc * fast_tanh(acc1[2]));
      float tv3 = rr16_add(uc * fast_tanh(acc1[3]));
      float selA = (l15 & 2) ? ((l15 & 1) ? sv3 : sv2)
                             : ((l15 & 1) ? sv1 : sv0);
      float selB = (l15 & 2) ? ((l15 & 1) ? tv3 : tv2)
                             : ((l15 & 1) ? tv1 : tv0);
      if (l15 < 4) {
        s_part[c & 1][lg * 4 + l15][w]      = selA;
        s_part[c & 1][16 + lg * 4 + l15][w] = selB;
      }
    }
  }

  /* ---- final deferred wsum (chunk CPB-1) ---- */
  asm volatile("s_waitcnt lgkmcnt(0)" ::: "memory");
  __builtin_amdgcn_s_barrier();
  asm volatile("" ::: "memory");
  wsum(CPB - 1);

  /* ---- block combine: 16 t-groups -> one partial per d ---- */
  asm volatile("s_waitcnt lgkmcnt(0)" ::: "memory");
  __builtin_amdgcn_s_barrier();
  asm volatile("" ::: "memory");
  float* comb = (float*)&Xl[0][0][0];   /* 16 KiB, overlays buffer 0 */
  #pragma unroll
  for (int j = 0; j < 8; ++j) comb[g * 256 + slice * 8 + j] = o8[j];
  if (slice == 0) l_part[g] = l_run;
  asm volatile("s_waitcnt lgkmcnt(0)" ::: "memory");
  __builtin_amdgcn_s_barrier();
  asm volatile("" ::: "memory");
  if (tid < 256) {
    float o = 0.f;
    #pragma unroll
    for (int g2 = 0; g2 < 16; ++g2) o += comb[g2 * 256 + tid];
    blk_o[(size_t)blk * D_N + tid] = o;
  }
  if (tid == 0) {
    float L = 0.f;
    #pragma unroll
    for (int g2 = 0; g2 < 16; ++g2) L += l_part[g2];
    blk_l[blk] = L;
  }
}

/* ---------- kernel 2: combine block-partials per batch ---------- */
__global__ __launch_bounds__(256)
void finalize(const float* __restrict__ blk_o, const float* __restrict__ blk_l,
              float* __restrict__ out) {
  const int b = blockIdx.x, d = threadIdx.x;
  float o = 0.f, L = 0.f;
  for (int i = 0; i < BLK_PER_B; ++i) {
    o += blk_o[(size_t)(b * BLK_PER_B + i) * D_N + d];
    L += blk_l[b * BLK_PER_B + i];
  }
  out[b * D_N + d] = o / L;
}

/* ---------- launch ---------- */
extern "C" void kernel_launch(void* const* d_in, const int* in_sizes, int n_in,
                              void* d_out, int out_size, void* d_ws, size_t ws_size,
                              hipStream_t stream) {
  const float* X = (const float*)d_in[0];
  const float* W = (const float*)d_in[1];
  const float* u = (const float*)d_in[2];
  float* out = (float*)d_out;

  float* blk_o = (float*)d_ws;                                      /* 512 KiB */
  float* blk_l = (float*)((char*)d_ws + (size_t)NBLOCKS * D_N * 4);

  attn_main<<<NBLOCKS, 512, 0, stream>>>(X, W, u, blk_o, blk_l);
  finalize<<<B_N, 256, 0, stream>>>(blk_o, blk_l, out);
}

// Round 17
// 52.279 us; speedup vs baseline: 2.3632x; 2.3632x over previous
//
#include <hip/hip_runtime.h>
#include <hip/hip_bf16.h>
#include <stdint.h>

#define B_N   32
#define T_N   8192
#define D_N   256
#define CTX_N 128
#define TB    32                      /* rows per chunk           */
#define CPB   16                      /* chunks per block         */
#define ROWS_PB (TB*CPB)              /* 512 rows per block       */
#define BLK_PER_B (T_N/ROWS_PB)       /* 16 blocks per batch      */
#define NBLOCKS (B_N*BLK_PER_B)       /* 512 = 2 per CU, all resident */
#define XP    264                     /* bf16 pitch (528 B rows)  */
#define SPW   12                      /* s_part row width (floats), 48B */

typedef unsigned short u16;
typedef unsigned int   u32;
typedef __attribute__((ext_vector_type(8))) short bf16x8;
typedef __attribute__((ext_vector_type(8))) unsigned short u16x8;
typedef __attribute__((ext_vector_type(4))) float f32x4;

__device__ __forceinline__ u16 f2bf(float f) {   /* compiler cast (RNE) */
  __hip_bfloat16 h = __float2bfloat16(f);
  return *reinterpret_cast<u16*>(&h);
}
__device__ __forceinline__ float bf2f(u16 h) {
  return __uint_as_float(((u32)h) << 16);
}
__device__ __forceinline__ float fast_tanh(float x) {
  float e = __expf(2.0f * x);
  return (e - 1.0f) * __builtin_amdgcn_rcpf(e + 1.0f);
}
/* 16-lane rotate-reduce on the VALU (DPP row_ror) — off the DS pipe.
   Leaves the full 16-lane sum in EVERY lane of the group. */
__device__ __forceinline__ float rr16_add(float v) {
  int x;
  x = __builtin_amdgcn_update_dpp(0, __float_as_int(v), 0x128, 0xF, 0xF, true); v += __int_as_float(x);
  x = __builtin_amdgcn_update_dpp(0, __float_as_int(v), 0x124, 0xF, 0xF, true); v += __int_as_float(x);
  x = __builtin_amdgcn_update_dpp(0, __float_as_int(v), 0x122, 0xF, 0xF, true); v += __int_as_float(x);
  x = __builtin_amdgcn_update_dpp(0, __float_as_int(v), 0x121, 0xF, 0xF, true); v += __int_as_float(x);
  return v;
}

/* ---------- kernel 1: fused scores+softmax+wsum ----------
   Round-15 structure (triple-buffer, ONE barrier/chunk, deferred wsum,
   CPB=16 all-resident, packed s_part writes, W folded into prologue).
   __launch_bounds__(512,4): 2 blocks/CU — the validated occupancy point. */
__global__ __launch_bounds__(512, 4)
void attn_main(const float* __restrict__ X, const float* __restrict__ W,
               const float* __restrict__ u,
               float* __restrict__ blk_o, float* __restrict__ blk_l) {
  __shared__ u16   Xl[3][TB][XP];                    /* 50688 B triple-buffer */
  __shared__ __align__(16) float s_part[2][TB][SPW]; /* 3072 B, parity       */
  __shared__ float l_part[16];

  const int tid = threadIdx.x;
  const int w   = tid >> 6;           /* wave 0..7: owns ctx cols w*16..+15 */
  const int l   = tid & 63;
  const int l15 = l & 15;
  const int lg  = l >> 4;

  const int blk  = blockIdx.x;
  const int b    = blk >> 4;                          /* / BLK_PER_B */
  const int rowB = (blk & (BLK_PER_B - 1)) * ROWS_PB;
  const float* Xbase = X + ((size_t)b * T_N + rowB) * D_N;

  /* staging map: thread = (row srow, 16-float segment scol) */
  const int srow = tid >> 4;          /* 0..31 */
  const int scol = (tid & 15) << 4;   /* 0,16,...,240 */
  const float* Xrow = Xbase + (size_t)srow * D_N + scol;

  /* ---- issue chunk-0 HBM prefetch FIRST (long latency) ---- */
  float4 pf0, pf1, pf2, pf3;
  pf0 = ((const float4*)Xrow)[0]; pf1 = ((const float4*)Xrow)[1];
  pf2 = ((const float4*)Xrow)[2]; pf3 = ((const float4*)Xrow)[3];

  /* ---- W^T fragments gathered from fp32 W (hidden under chunk-0 latency);
     bw[kk][j] = bf16(W[(kk*32+lg*8+j)][w*16+l15]) — identical RNE values
     to the old prep_w path, so output is bit-identical. 32 VGPRs. ---- */
  bf16x8 bw[8];
  {
    const float* wcol = W + (w * 16 + l15);
    #pragma unroll
    for (int kk = 0; kk < 8; ++kk) {
      #pragma unroll
      for (int j = 0; j < 8; ++j)
        bw[kk][j] = (short)f2bf(wcol[(size_t)(kk * 32 + lg * 8 + j) * CTX_N]);
    }
  }
  const float uc = u[w * 16 + l15];

  /* wsum map: thread = (t-pair g, d8 slice) */
  const int g     = tid >> 5;         /* 0..15 -> rows 2g,2g+1 */
  const int slice = tid & 31;         /* d = slice*8 .. +8     */
  float o8[8] = {0,0,0,0,0,0,0,0};
  float l_run = 0.f;

  /* deferred weighted-sum for chunk m (reads s_part[m&1], Xl[m%3]) */
  auto wsum = [&](int m) {
    const int pb = m % 3, sp = m & 1;
    float4 sa0 = *(const float4*)&s_part[sp][2 * g][0];
    float4 sa1 = *(const float4*)&s_part[sp][2 * g][4];
    float4 sb0 = *(const float4*)&s_part[sp][2 * g + 1][0];
    float4 sb1 = *(const float4*)&s_part[sp][2 * g + 1][4];
    float st0 = sa0.x; st0 += sa0.y; st0 += sa0.z; st0 += sa0.w;
    st0 += sa1.x; st0 += sa1.y; st0 += sa1.z; st0 += sa1.w;
    float st1 = sb0.x; st1 += sb0.y; st1 += sb0.z; st1 += sb0.w;
    st1 += sb1.x; st1 += sb1.y; st1 += sb1.z; st1 += sb1.w;
    float p0 = __expf(st0), p1 = __expf(st1);
    if (slice == 0) l_run += p0 + p1;
    u16x8 x0 = *(const u16x8*)&Xl[pb][2 * g][slice * 8];
    u16x8 x1 = *(const u16x8*)&Xl[pb][2 * g + 1][slice * 8];
    #pragma unroll
    for (int j = 0; j < 8; ++j) o8[j] += p0 * bf2f(x0[j]) + p1 * bf2f(x1[j]);
  };

  for (int c = 0; c < CPB; ++c) {
    const int cb = c % 3;

    /* ---- stage chunk c (fp32 regs -> bf16 LDS buf[c%3]) ---- */
    u16x8 s0, s1;
    s0[0]=f2bf(pf0.x); s0[1]=f2bf(pf0.y); s0[2]=f2bf(pf0.z); s0[3]=f2bf(pf0.w);
    s0[4]=f2bf(pf1.x); s0[5]=f2bf(pf1.y); s0[6]=f2bf(pf1.z); s0[7]=f2bf(pf1.w);
    s1[0]=f2bf(pf2.x); s1[1]=f2bf(pf2.y); s1[2]=f2bf(pf2.z); s1[3]=f2bf(pf2.w);
    s1[4]=f2bf(pf3.x); s1[5]=f2bf(pf3.y); s1[6]=f2bf(pf3.z); s1[7]=f2bf(pf3.w);
    *(u16x8*)&Xl[cb][srow][scol]     = s0;
    *(u16x8*)&Xl[cb][srow][scol + 8] = s1;

    /* ---- issue next chunk's global loads (fly across the barrier) ---- */
    if (c + 1 < CPB) {
      const float* sp_ = Xrow + (size_t)(c + 1) * TB * D_N;
      pf0 = ((const float4*)sp_)[0]; pf1 = ((const float4*)sp_)[1];
      pf2 = ((const float4*)sp_)[2]; pf3 = ((const float4*)sp_)[3];
    }

    asm volatile("s_waitcnt lgkmcnt(0)" ::: "memory");
    __builtin_amdgcn_s_barrier();     /* buf[c%3] + s_part[(c-1)&1] ready */
    asm volatile("" ::: "memory");

    /* ---- deferred wsum for chunk c-1 (overlaps MFMA region) ---- */
    if (c >= 1) wsum(c - 1);

    /* ---- scores chunk c: 32 rows x (this wave's 16 ctx cols), K=256 ---- */
    const u16* Xc = &Xl[cb][0][0];
    f32x4 acc0 = {0,0,0,0}, acc1 = {0,0,0,0};
    #pragma unroll
    for (int kk = 0; kk < 8; ++kk) {
      bf16x8 a0 = *(const bf16x8*)(Xc + l15 * XP + kk * 32 + lg * 8);
      bf16x8 a1 = *(const bf16x8*)(Xc + (16 + l15) * XP + kk * 32 + lg * 8);
      acc0 = __builtin_amdgcn_mfma_f32_16x16x32_bf16(a0, bw[kk], acc0, 0, 0, 0);
      acc1 = __builtin_amdgcn_mfma_f32_16x16x32_bf16(a1, bw[kk], acc1, 0, 0, 0);
    }
    /* s-partials: DPP reduce leaves sums in ALL lanes; select by l15 and
       write rows lg*4+l15 with lanes l15<4 -> 2 ds_write_b32 (was 8). */
    {
      float sv0 = rr16_add(uc * fast_tanh(acc0[0]));
      float sv1 = rr16_add(uc * fast_tanh(acc0[1]));
      float sv2 = rr16_add(uc * fast_tanh(acc0[2]));
      float sv3 = rr16_add(uc * fast_tanh(acc0[3]));
      float tv0 = rr16_add(uc * fast_tanh(acc1[0]));
      float tv1 = rr16_add(uc * fast_tanh(acc1[1]));
      float tv2 = rr16_add(uc * fast_tanh(acc1[2]));
      float tv3 = rr16_add(uc * fast_tanh(acc1[3]));
      float selA = (l15 & 2) ? ((l15 & 1) ? sv3 : sv2)
                             : ((l15 & 1) ? sv1 : sv0);
      float selB = (l15 & 2) ? ((l15 & 1) ? tv3 : tv2)
                             : ((l15 & 1) ? tv1 : tv0);
      if (l15 < 4) {
        s_part[c & 1][lg * 4 + l15][w]      = selA;
        s_part[c & 1][16 + lg * 4 + l15][w] = selB;
      }
    }
  }

  /* ---- final deferred wsum (chunk CPB-1) ---- */
  asm volatile("s_waitcnt lgkmcnt(0)" ::: "memory");
  __builtin_amdgcn_s_barrier();
  asm volatile("" ::: "memory");
  wsum(CPB - 1);

  /* ---- block combine: 16 t-groups -> one partial per d ---- */
  asm volatile("s_waitcnt lgkmcnt(0)" ::: "memory");
  __builtin_amdgcn_s_barrier();
  asm volatile("" ::: "memory");
  float* comb = (float*)&Xl[0][0][0];   /* 16 KiB, overlays buffer 0 */
  #pragma unroll
  for (int j = 0; j < 8; ++j) comb[g * 256 + slice * 8 + j] = o8[j];
  if (slice == 0) l_part[g] = l_run;
  asm volatile("s_waitcnt lgkmcnt(0)" ::: "memory");
  __builtin_amdgcn_s_barrier();
  asm volatile("" ::: "memory");
  if (tid < 256) {
    float o = 0.f;
    #pragma unroll
    for (int g2 = 0; g2 < 16; ++g2) o += comb[g2 * 256 + tid];
    blk_o[(size_t)blk * D_N + tid] = o;
  }
  if (tid == 0) {
    float L = 0.f;
    #pragma unroll
    for (int g2 = 0; g2 < 16; ++g2) L += l_part[g2];
    blk_l[blk] = L;
  }
}

/* ---------- kernel 2: combine block-partials per batch ---------- */
__global__ __launch_bounds__(256)
void finalize(const float* __restrict__ blk_o, const float* __restrict__ blk_l,
              float* __restrict__ out) {
  const int b = blockIdx.x, d = threadIdx.x;
  float o = 0.f, L = 0.f;
  for (int i = 0; i < BLK_PER_B; ++i) {
    o += blk_o[(size_t)(b * BLK_PER_B + i) * D_N + d];
    L += blk_l[b * BLK_PER_B + i];
  }
  out[b * D_N + d] = o / L;
}

/* ---------- launch ---------- */
extern "C" void kernel_launch(void* const* d_in, const int* in_sizes, int n_in,
                              void* d_out, int out_size, void* d_ws, size_t ws_size,
                              hipStream_t stream) {
  const float* X = (const float*)d_in[0];
  const float* W = (const float*)d_in[1];
  const float* u = (const float*)d_in[2];
  float* out = (float*)d_out;

  float* blk_o = (float*)d_ws;                                      /* 512 KiB */
  float* blk_l = (float*)((char*)d_ws + (size_t)NBLOCKS * D_N * 4);

  attn_main<<<NBLOCKS, 512, 0, stream>>>(X, W, u, blk_o, blk_l);
  finalize<<<B_N, 256, 0, stream>>>(blk_o, blk_l, out);
}